// Round 1
// baseline (16.624 us; speedup 1.0000x reference)
//
#include <hip/hip_runtime.h>

// 5-D separable cubic B-spline interpolation.
// Reference sums over the full 32^5 grid, but the basis has compact support:
// t = |(x-a)/h + 2 - i| is zero-weight for t > 2, i.e. only i in
// (g, g+4] with g = (x-a)/h contribute -> 4 taps per dim, 4^5 = 1024 taps total.
// One block per query point; 256 threads = 4^4 outer-dim combos; each thread
// does a 4-wide contiguous dot along the innermost dim, then block-reduce.

__global__ __launch_bounds__(256)
void spline5d_kernel(const float* __restrict__ x,   // [B,5]
                     const float* __restrict__ c,   // [32^5]
                     const float* __restrict__ a,   // [5]
                     const float* __restrict__ b,   // [5]
                     const float* __restrict__ n,   // [5]
                     float* __restrict__ out)       // [B]
{
    const int p = blockIdx.x;
    const int t = threadIdx.x;

    // Per-dim base offsets (0-based) and the 4 support weights, computed with
    // the same f32 expression as the reference so per-tap weights match.
    float w[5][4];
    int   o[5];
#pragma unroll
    for (int k = 0; k < 5; ++k) {
        const float hk = (b[k] - a[k]) / n[k];
        const float g  = (x[p * 5 + k] - a[k]) / hk;   // in [0, n)
        const int   fg = (int)floorf(g);
        o[k] = fg;                                     // 0-based index of first tap (i = fg+1)
#pragma unroll
        for (int j = 0; j < 4; ++j) {
            const float fi = (float)(fg + 1 + j);      // 1-based basis index i
            const float tt = fabsf(g + 2.0f - fi);     // == |(x-a)/h + 2 - i|
            const float t2 = tt * tt;
            const float win  = 4.0f - 6.0f * t2 + 3.0f * t2 * tt;
            const float e    = 2.0f - tt;
            const float wout = e * e * e;
            w[k][j] = (tt <= 1.0f) ? win : ((tt <= 2.0f) ? wout : 0.0f);
        }
    }

    // Thread -> (j0,j1,j2,j3) tap combo for dims 0..3.
    const int j3 = t & 3, j2 = (t >> 2) & 3, j1 = (t >> 4) & 3, j0 = (t >> 6) & 3;
    const float wprod = w[0][j0] * w[1][j1] * w[2][j2] * w[3][j3];

    // c is [32][32][32][32][32] row-major; innermost dim contiguous.
    const int base = ((((o[0] + j0) * 32 + (o[1] + j1)) * 32 + (o[2] + j2)) * 32
                      + (o[3] + j3)) * 32 + o[4];

    float s = 0.0f;
#pragma unroll
    for (int j4 = 0; j4 < 4; ++j4)
        s += w[4][j4] * c[base + j4];

    float v = wprod * s;

    // Block reduction: 4 waves of 64 lanes.
#pragma unroll
    for (int off = 32; off > 0; off >>= 1)
        v += __shfl_down(v, off, 64);

    __shared__ float part[4];
    if ((t & 63) == 0) part[t >> 6] = v;
    __syncthreads();
    if (t == 0) out[p] = part[0] + part[1] + part[2] + part[3];
}

extern "C" void kernel_launch(void* const* d_in, const int* in_sizes, int n_in,
                              void* d_out, int out_size, void* d_ws, size_t ws_size,
                              hipStream_t stream) {
    const float* x = (const float*)d_in[0];
    const float* c = (const float*)d_in[1];
    const float* a = (const float*)d_in[2];
    const float* b = (const float*)d_in[3];
    const float* n = (const float*)d_in[4];
    float* out = (float*)d_out;

    const int B = in_sizes[0] / 5;   // 64
    spline5d_kernel<<<B, 256, 0, stream>>>(x, c, a, b, n, out);
}

// Round 2
// 9.644 us; speedup vs baseline: 1.7238x; 1.7238x over previous
//
#include <hip/hip_runtime.h>

// 5-D separable cubic B-spline interpolation, latency-optimized.
// Compact support: only 4 taps per dim contribute -> 4^5 = 1024 taps/point.
// One 64-lane wave per query point. Each lane owns 4 of the 256 (i0..i3)
// combos and does a 4-wide contiguous dot along the innermost dim.
// All 16 coefficient loads are issued BEFORE the weight polynomials are
// evaluated so VALU work overlaps memory latency. Weights are computed
// inline per combo (no runtime-indexed register arrays -> no scratch).
// Reduction is pure wave-shuffle: no LDS, no __syncthreads.

__device__ __forceinline__ float bspl_w(float g, int o, int j) {
    // identical f32 expression to the reference: t = |(x-a)/h + 2 - i|
    const float fi = (float)(o + 1 + j);        // 1-based basis index i
    const float tt = fabsf(g + 2.0f - fi);
    const float t2 = tt * tt;
    const float win = 4.0f - 6.0f * t2 + 3.0f * t2 * tt;
    const float e   = 2.0f - tt;
    return (tt <= 1.0f) ? win : ((tt <= 2.0f) ? (e * e * e) : 0.0f);
}

__global__ __launch_bounds__(64)
void spline5d_kernel(const float* __restrict__ x,   // [B,5]
                     const float* __restrict__ c,   // [32^5]
                     const float* __restrict__ a,   // [5]
                     const float* __restrict__ b,   // [5]
                     const float* __restrict__ n,   // [5]
                     float* __restrict__ out)       // [B]
{
    const int p = blockIdx.x;
    const int t = threadIdx.x;   // 0..63

    // Per-dim normalized coord g and 0-based first-tap offset o.
    float g[5];
    int   o[5];
#pragma unroll
    for (int k = 0; k < 5; ++k) {
        const float hk = (b[k] - a[k]) / n[k];     // same op order as reference
        g[k] = (x[p * 5 + k] - a[k]) / hk;
        o[k] = (int)floorf(g[k]);
    }

    // Issue all 16 coefficient loads up front (independent, overlap latency).
    float cv[4][4];
    int jj0[4], jj1[4], jj2[4], jj3[4];
#pragma unroll
    for (int q = 0; q < 4; ++q) {
        const int m = t + (q << 6);                // 0..255, unique combo id
        jj3[q] = m & 3;
        jj2[q] = (m >> 2) & 3;
        jj1[q] = (m >> 4) & 3;
        jj0[q] = (m >> 6) & 3;
        const int base = ((((o[0] + jj0[q]) * 32 + (o[1] + jj1[q])) * 32
                           + (o[2] + jj2[q])) * 32 + (o[3] + jj3[q])) * 32 + o[4];
#pragma unroll
        for (int j4 = 0; j4 < 4; ++j4)
            cv[q][j4] = c[base + j4];              // innermost dim contiguous
    }

    // Innermost-dim weights (constant index -> registers).
    float w4[4];
#pragma unroll
    for (int j = 0; j < 4; ++j)
        w4[j] = bspl_w(g[4], o[4], j);

    // Accumulate: outer weights computed inline per combo.
    float v = 0.0f;
#pragma unroll
    for (int q = 0; q < 4; ++q) {
        float s = 0.0f;
#pragma unroll
        for (int j4 = 0; j4 < 4; ++j4)
            s += w4[j4] * cv[q][j4];
        const float wp = (bspl_w(g[0], o[0], jj0[q]) * bspl_w(g[1], o[1], jj1[q]))
                       * (bspl_w(g[2], o[2], jj2[q]) * bspl_w(g[3], o[3], jj3[q]));
        v += wp * s;
    }

    // Wave-wide reduction (64 lanes), no LDS.
#pragma unroll
    for (int off = 32; off > 0; off >>= 1)
        v += __shfl_down(v, off, 64);

    if (t == 0) out[p] = v;
}

extern "C" void kernel_launch(void* const* d_in, const int* in_sizes, int n_in,
                              void* d_out, int out_size, void* d_ws, size_t ws_size,
                              hipStream_t stream) {
    const float* x = (const float*)d_in[0];
    const float* c = (const float*)d_in[1];
    const float* a = (const float*)d_in[2];
    const float* b = (const float*)d_in[3];
    const float* n = (const float*)d_in[4];
    float* out = (float*)d_out;

    const int B = in_sizes[0] / 5;   // 64
    spline5d_kernel<<<B, 64, 0, stream>>>(x, c, a, b, n, out);
}

// Round 3
// 9.615 us; speedup vs baseline: 1.7290x; 1.0030x over previous
//
#include <hip/hip_runtime.h>

// 5-D separable cubic B-spline interpolation, latency-optimized v3.
// 4-tap compact support per dim -> 4^5 taps/point. One 64-lane wave per
// point; each lane owns 4 (i0..i3) combos (i0 == q is compile-time) and a
// 4-wide contiguous dot along the innermost dim.
// v3: closed-form matrix weights of u = frac(g) instead of 16 piecewise
// evaluations; 9 cndmask selections/lane; loads issued before weight math;
// single fp divide. No LDS, no barrier, pure shuffle reduction.

__device__ __forceinline__ void wcalc(float u, float& w0, float& w1,
                                      float& w2, float& w3) {
    // tap weights for j=0..3: (1-u)^3, 4-6u^2+3u^3, 4-6s^2+3s^3, u^3
    const float s = 1.0f - u;
    w0 = s * s * s;
    w3 = u * u * u;
    w1 = u * u * (3.0f * u - 6.0f) + 4.0f;
    w2 = s * s * (3.0f * s - 6.0f) + 4.0f;
}

__device__ __forceinline__ float sel4(float w0, float w1, float w2, float w3,
                                      int j) {
    float r = (j == 1) ? w1 : w0;
    r = (j == 2) ? w2 : r;
    r = (j == 3) ? w3 : r;
    return r;
}

__global__ __launch_bounds__(64)
void spline5d_kernel(const float* __restrict__ x,   // [B,5]
                     const float* __restrict__ c,   // [32^5]
                     const float* __restrict__ a,   // [5]
                     const float* __restrict__ b,   // [5]
                     const float* __restrict__ n,   // [5]
                     float* __restrict__ out)       // [B]
{
    const int p = blockIdx.x;
    const int t = threadIdx.x;   // 0..63

    // Per-dim base offset and fractional coordinate.
    float u[5];
    int   o[5];
#pragma unroll
    for (int k = 0; k < 5; ++k) {
        const float inv_h = n[k] / (b[k] - a[k]);
        const float g = (x[p * 5 + k] - a[k]) * inv_h;   // in [0, n)
        const int fg = (int)g;                            // g >= 0: trunc==floor
        o[k] = fg;
        u[k] = g - (float)fg;
    }

    const int j3 = t & 3, j2 = (t >> 2) & 3, j1 = (t >> 4) & 3;

    // Issue all 16 coefficient loads before any weight math.
    const int base0 = o[0] * 1048576 + (o[1] + j1) * 32768
                    + (o[2] + j2) * 1024 + (o[3] + j3) * 32 + o[4];
    float cv[4][4];
#pragma unroll
    for (int q = 0; q < 4; ++q) {
        const int bq = base0 + q * 1048576;   // i0 = o[0] + q
#pragma unroll
        for (int j4 = 0; j4 < 4; ++j4)
            cv[q][j4] = c[bq + j4];           // innermost dim contiguous
    }

    // Weights (overlap the load latency).
    float d0w[4];
    wcalc(u[0], d0w[0], d0w[1], d0w[2], d0w[3]);   // static-indexed below

    float w1a, w1b, w1c, w1d, w2a, w2b, w2c, w2d, w3a, w3b, w3c, w3d;
    wcalc(u[1], w1a, w1b, w1c, w1d);
    wcalc(u[2], w2a, w2b, w2c, w2d);
    wcalc(u[3], w3a, w3b, w3c, w3d);
    const float wbase = sel4(w1a, w1b, w1c, w1d, j1)
                      * sel4(w2a, w2b, w2c, w2d, j2)
                      * sel4(w3a, w3b, w3c, w3d, j3);

    float w40, w41, w42, w43;
    wcalc(u[4], w40, w41, w42, w43);

    float acc = 0.0f;
#pragma unroll
    for (int q = 0; q < 4; ++q) {
        float s = w40 * cv[q][0];
        s = fmaf(w41, cv[q][1], s);
        s = fmaf(w42, cv[q][2], s);
        s = fmaf(w43, cv[q][3], s);
        acc = fmaf(d0w[q], s, acc);
    }
    float v = wbase * acc;

    // 64-lane shuffle reduction, no LDS.
#pragma unroll
    for (int off = 32; off > 0; off >>= 1)
        v += __shfl_down(v, off, 64);

    if (t == 0) out[p] = v;
}

extern "C" void kernel_launch(void* const* d_in, const int* in_sizes, int n_in,
                              void* d_out, int out_size, void* d_ws, size_t ws_size,
                              hipStream_t stream) {
    const float* x = (const float*)d_in[0];
    const float* c = (const float*)d_in[1];
    const float* a = (const float*)d_in[2];
    const float* b = (const float*)d_in[3];
    const float* n = (const float*)d_in[4];
    float* out = (float*)d_out;

    const int B = in_sizes[0] / 5;   // 64
    spline5d_kernel<<<B, 64, 0, stream>>>(x, c, a, b, n, out);
}